// Round 6
// baseline (38.726 us; speedup 1.0000x reference)
//
#include <hip/hip_runtime.h>
#include <hip/hip_bf16.h>

typedef __attribute__((ext_vector_type(8))) short short8;   // 8 bf16 (4 VGPRs)
typedef __attribute__((ext_vector_type(4))) float f32x4;    // MFMA acc

#define NPTS 131072

__device__ inline unsigned short f2bf(float f) {
    unsigned u = __float_as_uint(f);
    u = (u + 0x7FFFu + ((u >> 16) & 1u)) >> 16;   // RNE
    return (unsigned short)u;
}

__device__ inline unsigned pack2(float a, float b) {
    union { __hip_bfloat162 h; unsigned u; } v;
    v.h = __float22bfloat162_rn(float2{a, b});    // v_cvt_pk_bf16_f32 (RNE)
    return v.u;
}

// ---------------- prep: bf16 MFMA-ready weight tables + padded bones --------
// w1t[e][k]     : k 0..15 = (Ws@W1) qcf channels, 16..18 = win rows, 19..31 = 0
// w2t[e][pi(d)] : = W2[d][e], pi(d) = (d&15)*8 + (d>>4)
// beff[e]       : b1[e] + bs @ W1[0:128]
// w3t[q][k]     : block-diag W3 in sigma-permuted K, sigma(e) = (e&15)*2 + (e>>4)
// bones4[m]     : {x,y,z,0} float4-padded bones
__global__ __launch_bounds__(256) void prep_kernel(
    const float* __restrict__ Ws, const float* __restrict__ bs,
    const float* __restrict__ W1, const float* __restrict__ b1,
    const float* __restrict__ W2, const float* __restrict__ W3,
    const float* __restrict__ bones,
    unsigned short* __restrict__ w1t, unsigned short* __restrict__ w2t,
    float* __restrict__ beff, unsigned short* __restrict__ w3t,
    float* __restrict__ bones4)
{
    int t = blockIdx.x * 256 + threadIdx.x;
    if (t < 4096) {
        int e = t >> 5, k = t & 31;
        float v = 0.f;
        if (k < 16) {
            for (int d = 0; d < 128; ++d) v = fmaf(Ws[k*128 + d], W1[d*128 + e], v);
        } else if (k < 19) {
            v = W1[(128 + (k - 16))*128 + e];
        }
        w1t[e*32 + k] = f2bf(v);
    } else if (t < 8192) {
        int t2 = t - 4096;
        int e = t2 >> 7, d = t2 & 127;
        w2t[e*128 + ((d & 15)*8 + (d >> 4))] = f2bf(W2[d*32 + e]);
    } else if (t < 8320) {
        int e = t - 8192;
        float v = b1[e];
        for (int d = 0; d < 128; ++d) v = fmaf(bs[d], W1[d*128 + e], v);
        beff[e] = v;
    } else if (t < 8832) {
        int i = t - 8320;
        int q = i >> 5, k = i & 31;
        int e = (k & 1)*16 + (k >> 1);        // sigma^-1(k)
        int r = e >> 3, f = e & 7;
        float v = 0.f;
        if (q < 12) {
            int r2 = q / 3, o = q - r2*3;
            if (r == r2) v = W3[f*3 + o];
        }
        w3t[q*32 + k] = f2bf(v);
    } else if (t < 8832 + 4*8192) {
        int i = t - 8832;
        int id = i >> 2, c = i & 3;
        bones4[i] = (c < 3) ? bones[id*3 + c] : 0.f;
    }
}

// ---------------- main fused kernel: 1 wave / block, 16 points / wave -------
// LDS only for the two MFMA-layout transposes:
//   H1b : 16 x 136 bf16 (272 B stride) = 4352 B  (pi-permuted cols)
//   H2p : 16 x 40  bf16 (80 B stride)  = 1280 B  (sigma-permuted cols)
__global__ __launch_bounds__(64, 2) void decoder_kernel(
    const float* __restrict__ qcf, const int* __restrict__ didx,
    const float* __restrict__ dwin, const float* __restrict__ bones4,
    const unsigned short* __restrict__ w1t, const unsigned short* __restrict__ w2t,
    const float* __restrict__ beff, const float* __restrict__ b2,
    const unsigned short* __restrict__ w3t, const float* __restrict__ b3,
    float* __restrict__ out)
{
    __shared__ unsigned short H1b[16 * 136];
    __shared__ unsigned short H2p[16 * 40];

    const int lane = threadIdx.x;
    const int q4   = lane >> 4;
    const int l16  = lane & 15;

    const int base = blockIdx.x * 16;
    const int p    = base + l16;      // this lane's point

    // ---- hoisted wave-invariant weight fragments ---------------------------
    short8 W1f[8]; float beffv[8];
#pragma unroll
    for (int dt = 0; dt < 8; ++dt) {
        W1f[dt]   = *(const short8*)(w1t + (dt*16 + l16)*32 + q4*8);
        beffv[dt] = beff[dt*16 + l16];
    }
    short8 W2f[2][4]; float b2v[2];
#pragma unroll
    for (int et = 0; et < 2; ++et) {
        b2v[et] = b2[et*16 + l16];
#pragma unroll
        for (int kt = 0; kt < 4; ++kt)
            W2f[et][kt] = *(const short8*)(w2t + (et*16 + l16)*128 + kt*32 + q4*8);
    }
    const short8 w3f = *(const short8*)(w3t + l16*32 + q4*8);
    const int   o3c  = l16 - (l16/3)*3;
    const float b3o  = (l16 < 12) ? b3[o3c] : 0.f;

    // ---- per-lane gather + IDW weights (no LDS, no shuffles) ---------------
    const int4 ia = *(const int4*)(didx + p*8);
    const int4 ib = *(const int4*)(didx + p*8 + 4);
    const int id[8] = { ia.x, ia.y, ia.z, ia.w, ib.x, ib.y, ib.z, ib.w };
    const float wx = dwin[p*3+0], wy = dwin[p*3+1], wz = dwin[p*3+2];

    const float4* __restrict__ bn4 = (const float4*)bones4;
    float w[8]; float s = 0.f;
#pragma unroll
    for (int k = 0; k < 8; ++k) {
        const float4 b = bn4[id[k]];
        const float rx = wx - b.x, ry = wy - b.y, rz = wz - b.z;
        const float dist = sqrtf(fmaf(rx,rx, fmaf(ry,ry, fmaf(rz,rz, 1e-8f))));
        w[k] = 1.0f / (dist + 1e-8f);
        s += w[k];
    }
    const float inv = 1.0f / s;

    // ---- interp directly into the L1 A-fragment layout ---------------------
    // lane holds A[row=l16][k=q4*8+j]: q4<2 -> qcf channels, q4==2 -> window.
    union { unsigned u[4]; short8 s8; } a1u;
    a1u.u[0] = a1u.u[1] = a1u.u[2] = a1u.u[3] = 0u;
    if (q4 < 2) {
        float acc[8] = {0.f,0.f,0.f,0.f,0.f,0.f,0.f,0.f};
        const float4* __restrict__ q4p = (const float4*)qcf;
#pragma unroll
        for (int k = 0; k < 8; ++k) {
            const float4 lo = q4p[id[k]*4 + q4*2 + 0];
            const float4 hi = q4p[id[k]*4 + q4*2 + 1];
            acc[0] = fmaf(w[k], lo.x, acc[0]);
            acc[1] = fmaf(w[k], lo.y, acc[1]);
            acc[2] = fmaf(w[k], lo.z, acc[2]);
            acc[3] = fmaf(w[k], lo.w, acc[3]);
            acc[4] = fmaf(w[k], hi.x, acc[4]);
            acc[5] = fmaf(w[k], hi.y, acc[5]);
            acc[6] = fmaf(w[k], hi.z, acc[6]);
            acc[7] = fmaf(w[k], hi.w, acc[7]);
        }
        a1u.u[0] = pack2(acc[0]*inv, acc[1]*inv);
        a1u.u[1] = pack2(acc[2]*inv, acc[3]*inv);
        a1u.u[2] = pack2(acc[4]*inv, acc[5]*inv);
        a1u.u[3] = pack2(acc[6]*inv, acc[7]*inv);
    } else if (q4 == 2) {
        a1u.u[0] = pack2(wx, wy);
        a1u.u[1] = pack2(wz, 0.f);
    }

    // ---- layer 1: [16x32] @ [32x128] via 8 MFMA ----------------------------
    f32x4 acc1[8];
#pragma unroll
    for (int dt = 0; dt < 8; ++dt) {
        f32x4 c = { beffv[dt], beffv[dt], beffv[dt], beffv[dt] };
        acc1[dt] = __builtin_amdgcn_mfma_f32_16x16x32_bf16(a1u.s8, W1f[dt], c, 0, 0, 0);
    }
    // relu + pack to pi-permuted H1: lane owns cols l16*8+dt -> 4x b128 write
#pragma unroll
    for (int r = 0; r < 4; ++r) {
        union { unsigned u[4]; short8 s8; } pk;
        pk.u[0] = pack2(fmaxf(acc1[0][r],0.f), fmaxf(acc1[1][r],0.f));
        pk.u[1] = pack2(fmaxf(acc1[2][r],0.f), fmaxf(acc1[3][r],0.f));
        pk.u[2] = pack2(fmaxf(acc1[4][r],0.f), fmaxf(acc1[5][r],0.f));
        pk.u[3] = pack2(fmaxf(acc1[6][r],0.f), fmaxf(acc1[7][r],0.f));
        *(short8*)(H1b + (q4*4 + r)*136 + l16*8) = pk.s8;
    }
    __syncthreads();

    // ---- layer 2: [16x128] @ [128x32] via 8 MFMA (pi-space K) --------------
    f32x4 acc2[2] = { { b2v[0], b2v[0], b2v[0], b2v[0] },
                      { b2v[1], b2v[1], b2v[1], b2v[1] } };
#pragma unroll
    for (int kt = 0; kt < 4; ++kt) {
        const short8 a2 = *(const short8*)(H1b + l16*136 + kt*32 + q4*8);
        acc2[0] = __builtin_amdgcn_mfma_f32_16x16x32_bf16(a2, W2f[0][kt], acc2[0], 0, 0, 0);
        acc2[1] = __builtin_amdgcn_mfma_f32_16x16x32_bf16(a2, W2f[1][kt], acc2[1], 0, 0, 0);
    }
    // relu + pack to sigma-permuted H2: lane owns cols l16*2+et
#pragma unroll
    for (int r = 0; r < 4; ++r) {
        unsigned p01 = pack2(fmaxf(acc2[0][r],0.f), fmaxf(acc2[1][r],0.f));
        *(unsigned*)(H2p + (q4*4 + r)*40 + l16*2) = p01;
    }
    __syncthreads();

    // ---- layer 3: [16x32] @ [32x12] via 1 MFMA + residual ------------------
    const short8 a3 = *(const short8*)(H2p + l16*40 + q4*8);
    f32x4 c3 = { b3o, b3o, b3o, b3o };
    f32x4 o3 = __builtin_amdgcn_mfma_f32_16x16x32_bf16(a3, w3f, c3, 0, 0, 0);
    if (l16 < 12) {
#pragma unroll
        for (int r = 0; r < 4; ++r) {
            const int pt = base + q4*4 + r;
            out[(size_t)pt*12 + l16] = dwin[pt*3 + o3c] + o3[r];
        }
    }
}

extern "C" void kernel_launch(void* const* d_in, const int* in_sizes, int n_in,
                              void* d_out, int out_size, void* d_ws, size_t ws_size,
                              hipStream_t stream) {
    const float* qcf   = (const float*)d_in[0];
    const int*   didx  = (const int*)  d_in[1];
    const float* dwin  = (const float*)d_in[2];
    const float* bones = (const float*)d_in[3];
    // d_in[4] = K (always 8)
    const float* Ws = (const float*)d_in[5];
    const float* bs = (const float*)d_in[6];
    const float* W1 = (const float*)d_in[7];
    const float* b1 = (const float*)d_in[8];
    const float* W2 = (const float*)d_in[9];
    const float* b2 = (const float*)d_in[10];
    const float* W3 = (const float*)d_in[11];
    const float* b3 = (const float*)d_in[12];
    float* out = (float*)d_out;

    unsigned short* w1t    = (unsigned short*)d_ws;                    // 8 KB
    unsigned short* w2t    = (unsigned short*)((char*)d_ws + 8192);    // 8 KB
    float*          beff   = (float*)((char*)d_ws + 16384);            // 512 B
    unsigned short* w3t    = (unsigned short*)((char*)d_ws + 16896);   // 1 KB
    float*          bones4 = (float*)((char*)d_ws + 17920);            // 128 KB

    hipLaunchKernelGGL(prep_kernel, dim3(163), dim3(256), 0, stream,
                       Ws, bs, W1, b1, W2, W3, bones, w1t, w2t, beff, w3t, bones4);
    hipLaunchKernelGGL(decoder_kernel, dim3(NPTS/16), dim3(64), 0, stream,
                       qcf, didx, dwin, bones4, w1t, w2t, beff, b2, w3t, b3, out);
}